// Round 9
// baseline (528.182 us; speedup 1.0000x reference)
//
#include <hip/hip_runtime.h>
#include <math.h>

#define NTOK 131072
#define EMB  2048
#define UDIM 128
#define KDIM 2176   // EMB + UDIM
#define NE   64
#define TOPK 8

#define BM     128   // tokens per block (4 waves x 32 tokens)
#define NKSTEP 68    // KDIM / 32 (MFMA K-steps)
#define LSTR   65    // f32 logits row stride in LDS
#define MARGIN 1e-4f // rank-8/9 gap below which we recompute in f64
#define WPLANE ((size_t)NKSTEP * 64 * 32)   // bf16 elems per W plane

typedef short bf16x8 __attribute__((ext_vector_type(8)));
typedef float f32x4  __attribute__((ext_vector_type(4)));

union FragU { uint4 u; bf16x8 v; };

__device__ __forceinline__ unsigned rnbf(unsigned u) {
    // round-to-nearest-even f32 -> bf16 (result in top 16 bits)
    return u + 0x7FFFu + ((u >> 16) & 1u);
}

// 8 f32 -> packed bf16 hi plane + lo plane (proven RNE split, round 3)
__device__ __forceinline__ void cvt8(const float4 a, const float4 b,
                                     uint4& hi, uint4& lo) {
    const float x[8] = {a.x, a.y, a.z, a.w, b.x, b.y, b.z, b.w};
    unsigned hh[4], ll[4];
    #pragma unroll
    for (int p = 0; p < 4; ++p) {
        const unsigned u0 = __float_as_uint(x[2*p]);
        const unsigned u1 = __float_as_uint(x[2*p+1]);
        const unsigned r0 = rnbf(u0), r1 = rnbf(u1);
        hh[p] = (r0 >> 16) | (r1 & 0xFFFF0000u);
        const float h0 = __uint_as_float(r0 & 0xFFFF0000u);
        const float h1 = __uint_as_float(r1 & 0xFFFF0000u);
        const unsigned s0 = rnbf(__float_as_uint(x[2*p]   - h0));
        const unsigned s1 = rnbf(__float_as_uint(x[2*p+1] - h1));
        ll[p] = (s0 >> 16) | (s1 & 0xFFFF0000u);
    }
    hi = make_uint4(hh[0], hh[1], hh[2], hh[3]);
    lo = make_uint4(ll[0], ll[1], ll[2], ll[3]);
}

// W f32 -> bf16 hi/lo planes in per-lane fragment order:
// wh[(ks*64 + e)*32 + lk*8 + j] = bf16(W[e][ks*32 + lk*8 + j])
__global__ __launch_bounds__(256)
void prep_w(const float* __restrict__ W,
            unsigned short* __restrict__ wh,
            unsigned short* __restrict__ wl)
{
    const int t = blockIdx.x * 256 + threadIdx.x;   // [0, 68*64*4)
    if (t >= NKSTEP * 64 * 4) return;
    const int lk = t & 3, e = (t >> 2) & 63, ks = t >> 8;
    const float* p = W + (size_t)e * KDIM + ks * 32 + lk * 8;
    const float4 a = *reinterpret_cast<const float4*>(p);
    const float4 c = *reinterpret_cast<const float4*>(p + 4);
    uint4 hi, lo;
    cvt8(a, c, hi, lo);
    const size_t di = ((size_t)ks * 64 + e) * 32 + lk * 8;
    *reinterpret_cast<uint4*>(wh + di) = hi;
    *reinterpret_cast<uint4*>(wl + di) = lo;
}

__global__ void zero_flags(int* flagbuf) {
    if (threadIdx.x == 0 && blockIdx.x == 0) flagbuf[0] = 0;
}

__global__ __launch_bounds__(256)
void gate_main(const float* __restrict__ h,
               const float* __restrict__ u,
               const unsigned short* __restrict__ wh,
               const unsigned short* __restrict__ wl,
               const float* __restrict__ b,
               int* __restrict__ flagbuf,
               float* __restrict__ out)
{
    __shared__ __align__(16) float ls[BM * LSTR];   // 33280 B
    __shared__ int flaglist[BM];
    __shared__ int nflag;

    const int tid  = threadIdx.x;
    const int lane = tid & 63;
    const int wid  = tid >> 6;    // 4 waves, 32 tokens each
    const int bm   = blockIdx.x * BM;
    const int lrow = lane & 15;   // fragment row/col
    const int lk   = lane >> 4;   // fragment k-quarter

    if (tid == 0) nflag = 0;

    f32x4 acc[2][4];
    #pragma unroll
    for (int mi = 0; mi < 2; ++mi)
        #pragma unroll
        for (int ni = 0; ni < 4; ++ni)
            acc[mi][ni] = (f32x4){0.f, 0.f, 0.f, 0.f};

    // W fragment loads for one ks: 8 x uint4 (4 hi + 4 lo), L2-resident
    FragU  wf[2][8];
    float4 x[4][4];     // X ring: 4 phases deep, 4 float4 per phase per lane

    auto wfLoad = [&](int ks, FragU* wfb) {
        const uint4* bH = reinterpret_cast<const uint4*>(wh + (size_t)ks * 2048);
        const uint4* bL = reinterpret_cast<const uint4*>(wl + (size_t)ks * 2048);
        #pragma unroll
        for (int ni = 0; ni < 4; ++ni) {
            const int off = (ni*16 + lrow)*4 + lk;
            wfb[ni]    .u = bH[off];
            wfb[4 + ni].u = bL[off];
        }
    };
    auto xLoad = [&](int ks, float4* xb, int src) {
        const float* s  = src ? u : h;
        const int    ld = src ? UDIM : EMB;
        const int    col = ks*32 - (src ? EMB : 0) + lk*8;
        #pragma unroll
        for (int mi = 0; mi < 2; ++mi) {
            const size_t ro = (size_t)(bm + wid*32 + mi*16 + lrow) * ld + col;
            xb[mi*2 + 0] = *reinterpret_cast<const float4*>(s + ro);
            xb[mi*2 + 1] = *reinterpret_cast<const float4*>(s + ro + 4);
        }
    };

// One pipeline phase. I is a compile-time buffer index (== KS & 3).
// Order matters: (1) next-W issue, (2) cvt8 current X (VALU), (3) re-issue X
// ring slot, (4) MFMAs. The MFMA wait for wf[I&1] then leaves exactly the
// 12 loads issued in (1)+(3) in flight -> counted vmcnt by construction.
#define PHASE(I, KS, WNEXT, XSRC) do {                                          \
    if (WNEXT) wfLoad((KS) + 1, wf[((I) + 1) & 1]);                             \
    FragU ah0, al0, ah1, al1;                                                   \
    cvt8(x[(I) & 3][0], x[(I) & 3][1], ah0.u, al0.u);                           \
    cvt8(x[(I) & 3][2], x[(I) & 3][3], ah1.u, al1.u);                           \
    if ((XSRC) >= 0) xLoad((KS) + 4, x[(I) & 3], (XSRC));                       \
    FragU* wc = wf[(I) & 1];                                                    \
    _Pragma("unroll")                                                           \
    for (int ni = 0; ni < 4; ++ni) {                                            \
        acc[0][ni] = __builtin_amdgcn_mfma_f32_16x16x32_bf16(ah0.v, wc[ni].v,     acc[0][ni], 0, 0, 0); \
        acc[0][ni] = __builtin_amdgcn_mfma_f32_16x16x32_bf16(ah0.v, wc[4+ni].v,   acc[0][ni], 0, 0, 0); \
        acc[0][ni] = __builtin_amdgcn_mfma_f32_16x16x32_bf16(al0.v, wc[ni].v,     acc[0][ni], 0, 0, 0); \
        acc[1][ni] = __builtin_amdgcn_mfma_f32_16x16x32_bf16(ah1.v, wc[ni].v,     acc[1][ni], 0, 0, 0); \
        acc[1][ni] = __builtin_amdgcn_mfma_f32_16x16x32_bf16(ah1.v, wc[4+ni].v,   acc[1][ni], 0, 0, 0); \
        acc[1][ni] = __builtin_amdgcn_mfma_f32_16x16x32_bf16(al1.v, wc[ni].v,     acc[1][ni], 0, 0, 0); \
    }                                                                           \
} while (0)

    // ---- prologue: W(0) + X(0..3) in flight ----
    wfLoad(0, wf[0]);
    xLoad(0, x[0], 0);
    xLoad(1, x[1], 0);
    xLoad(2, x[2], 0);
    xLoad(3, x[3], 0);

    // ---- main loop: ks 0..59, all X prefetch from h, branch-free ----
    #pragma unroll 1
    for (int g = 0; g < 15; ++g) {
        const int ks = g * 4;
        PHASE(0, ks + 0, 1, 0);
        PHASE(1, ks + 1, 1, 0);
        PHASE(2, ks + 2, 1, 0);
        PHASE(3, ks + 3, 1, 0);
    }
    // ---- ks 60..63: X prefetch crosses into u ----
    PHASE(0, 60, 1, 1);
    PHASE(1, 61, 1, 1);
    PHASE(2, 62, 1, 1);
    PHASE(3, 63, 1, 1);
    // ---- ks 64..67: drain, no X issue ----
    PHASE(0, 64, 1, -1);
    PHASE(1, 65, 1, -1);
    PHASE(2, 66, 1, -1);
    PHASE(3, 67, 0, -1);

#undef PHASE

    // ---- C-write: logits + bias into f32 LDS ----
    #pragma unroll
    for (int mi = 0; mi < 2; ++mi)
        #pragma unroll
        for (int ni = 0; ni < 4; ++ni) {
            const float be = b[ni*16 + lrow];
            #pragma unroll
            for (int r = 0; r < 4; ++r) {
                const int tl = wid*32 + mi*16 + lk*4 + r;
                const int e  = ni*16 + lrow;
                ls[tl * LSTR + e] = acc[mi][ni][r] + be;
            }
        }
    __syncthreads();

    // ---- per-token top-8 + margin + softmax (1 thread : 1 token) ----
    if (tid < BM) {
        float* row = ls + tid * LSTR;
        unsigned long long selm = 0ULL;
        float mx = 0.f, l8 = 0.f, l9 = 0.f;
        for (int s = 0; s < TOPK + 1; ++s) {
            float best = -1e30f; int bi = 0;
            #pragma unroll
            for (int e = 0; e < NE; ++e) {
                const float v = row[e];
                if (!((selm >> e) & 1ULL) && v > best) { best = v; bi = e; }
            }
            if (s == 0) mx = best;
            if (s < TOPK) selm |= 1ULL << bi;
            if (s == TOPK - 1) l8 = best;
            if (s == TOPK)     l9 = best;
        }
        if (l8 - l9 < MARGIN) {
            const int slot = atomicAdd(&nflag, 1);
            flaglist[slot] = tid;
        }
        float tot = 0.f, s8 = 0.f;
        #pragma unroll
        for (int e = 0; e < NE; ++e) {
            const float p = __expf(row[e] - mx);
            tot += p;
            if ((selm >> e) & 1ULL) s8 += p;
            row[e] = p;
        }
        const float inv = 1.f / (s8 + 1e-9f * tot);
        #pragma unroll
        for (int e = 0; e < NE; ++e)
            row[e] = ((selm >> e) & 1ULL) ? row[e] * inv : 0.f;
    }
    __syncthreads();

    // ---- coalesced float4 store ----
    {
        const int tx = tid & 15, ty = tid >> 4;
        #pragma unroll
        for (int r = 0; r < 8; ++r) {
            const int m = ty + r * 16;
            float4 v;
            v.x = ls[m * LSTR + tx*4 + 0];
            v.y = ls[m * LSTR + tx*4 + 1];
            v.z = ls[m * LSTR + tx*4 + 2];
            v.w = ls[m * LSTR + tx*4 + 3];
            *reinterpret_cast<float4*>(out + (size_t)(bm + m) * NE + tx*4) = v;
        }
    }

    // ---- publish flagged tokens for the refine kernel (device-scope atomics) ----
    if (tid < nflag) {
        const int slot = atomicAdd(flagbuf, 1);
        flagbuf[1 + slot] = bm + flaglist[tid];
    }
}

// ---- exact f64 referee for margin-flagged tokens (reads original f32 W) ----
__global__ __launch_bounds__(256)
void gate_refine(const float* __restrict__ h,
                 const float* __restrict__ u,
                 const float* __restrict__ W,
                 const float* __restrict__ b,
                 const int* __restrict__ flagbuf,   // [0]=count, then token ids
                 float* __restrict__ out)
{
    __shared__ double dscr[576];
    const int nf = flagbuf[0];
    for (int f = blockIdx.x; f < nf; f += gridDim.x) {
        const int tok  = flagbuf[1 + f];
        const int tid  = threadIdx.x;
        const int e    = tid & 63;
        const int part = tid >> 6;          // 4 K-partitions x 544
        const int ka = part * 544, kb2 = ka + 544;
        double s = 0.0;
        #pragma unroll 4
        for (int k = ka; k < kb2; ++k) {
            const float xv = (k < EMB) ? h[(size_t)tok * EMB + k]
                                       : u[(size_t)tok * UDIM + (k - EMB)];
            s = fma((double)xv, (double)W[(size_t)e * KDIM + k], s);
        }
        dscr[part * 64 + e] = s;
        __syncthreads();
        if (tid < NE) {
            const double l = dscr[tid] + dscr[64 + tid] + dscr[128 + tid] +
                             dscr[192 + tid] + (double)b[tid];
            dscr[512 + tid] = l;
        }
        __syncthreads();
        if (tid == 0) {
            double* dl = dscr + 512;
            double mx = dl[0];
            #pragma unroll
            for (int e2 = 1; e2 < NE; ++e2) mx = fmax(mx, dl[e2]);
            double tot = 0.0;
            #pragma unroll
            for (int e2 = 0; e2 < NE; ++e2) {
                const double p = exp(dl[e2] - mx);
                dl[e2] = p;
                tot += p;
            }
            double s8 = 0.0;
            for (int ss = 0; ss < TOPK; ++ss) {
                double best = -1.0; int bi = 0;
                for (int e2 = 0; e2 < NE; ++e2) {
                    const double p = dl[e2];
                    if (p > best) { best = p; bi = e2; }
                }
                s8 += best;
                dl[bi] = -best;
            }
            const double inv = 1.0 / (s8 + 1e-9 * tot);
            for (int e2 = 0; e2 < NE; ++e2) {
                const double p = dl[e2];
                out[(size_t)tok * NE + e2] = (float)((p < 0.0) ? (-p) * inv : 0.0);
            }
        }
        __syncthreads();
    }
}

extern "C" void kernel_launch(void* const* d_in, const int* in_sizes, int n_in,
                              void* d_out, int out_size, void* d_ws, size_t ws_size,
                              hipStream_t stream) {
    const float* h = (const float*)d_in[0];
    const float* u = (const float*)d_in[1];
    const float* W = (const float*)d_in[2];
    const float* b = (const float*)d_in[3];
    float* out = (float*)d_out;
    (void)in_sizes; (void)n_in; (void)out_size; (void)ws_size;

    unsigned short* wh = (unsigned short*)d_ws;
    unsigned short* wl = wh + WPLANE;
    int* flagbuf = (int*)(wl + WPLANE);   // [0]=count, then up to NTOK ids

    hipLaunchKernelGGL(zero_flags, dim3(1), dim3(64), 0, stream, flagbuf);
    hipLaunchKernelGGL(prep_w, dim3(NKSTEP), dim3(256), 0, stream, W, wh, wl);
    hipLaunchKernelGGL(gate_main, dim3(NTOK / BM), dim3(256), 0, stream,
                       h, u, wh, wl, b, flagbuf, out);
    hipLaunchKernelGGL(gate_refine, dim3(256), dim3(256), 0, stream,
                       h, u, W, b, flagbuf, out);
}